// Round 8
// baseline (23431.546 us; speedup 1.0000x reference)
//
#include <hip/hip_runtime.h>
#include <stdint.h>

#define B_   128
#define T_   4096
#define F_   64
#define H0_  77
#define H1_  51
#define H2_  128
#define K0_  141
#define K1_  128
#define K2_  179
// 256 threads, ONE lane per unit (unit == tid). 4 waves/CU, 1 wave/SIMD ->
// 256-VGPR budget (measured pool law: 512 regs/SIMD / waves_per_SIMD).
// W1,W2 packed-fp16 pairs live in VGPRs (2 x 92 u32 = 184 regs); folded
// (Wa+Wb) lives in LDS index-major [23][256] float4 (lane-consecutive
// ds_read_b128, conflict-free). z is fp16 pairs in LDS -> reads are
// wave-uniform (broadcast, free) and half as many as fp32.
#define NG   23            // float4 groups (8 fp16 values) per row slice
#define NW   (4 * NG)      // 92 packed u32 pairs per matrix per lane
#define ZROWV 192          // fp16 values per z row (zero-padded)
#define ZBUFV (3 * ZROWV)  // 576 values per z buffer; double-buffered

typedef _Float16 half2_t __attribute__((ext_vector_type(2)));

__device__ inline float bf2f(unsigned short v) {
    unsigned u = ((unsigned)v) << 16;
    return __builtin_bit_cast(float, u);
}
__device__ inline unsigned short f2bf(float f) {
    unsigned u = __builtin_bit_cast(unsigned, f);
    unsigned r = (u + 0x7FFFu + ((u >> 16) & 1u)) >> 16;   // RNE, finite values
    return (unsigned short)r;
}
__device__ inline uint32_t packh2(float a, float b) {
    half2_t h; h.x = (_Float16)a; h.y = (_Float16)b;
    return __builtin_bit_cast(uint32_t, h);
}
__device__ inline half2_t u2h(uint32_t u) { return __builtin_bit_cast(half2_t, u); }

// dt: 0 = fp32, 1 = bf16, 2 = fp16
__device__ inline float ldany(const void* p, size_t i, int dt) {
    if (dt == 0) return ((const float*)p)[i];
    if (dt == 1) return bf2f(((const unsigned short*)p)[i]);
    return (float)((const _Float16*)p)[i];
}
__device__ inline void stout(void* p, size_t i, float v, int dt) {
    if (dt == 0)      ((float*)p)[i] = v;
    else if (dt == 1) ((unsigned short*)p)[i] = f2bf(v);
    else              ((_Float16*)p)[i] = (_Float16)v;
}

__device__ inline float sigm_f(float x) { return 1.0f / (1.0f + __expf(-x)); }
__device__ inline float tanh_f(float x) { return 2.0f / (1.0f + __expf(-2.0f * x)) - 1.0f; }

// fp16-pair dot with fp32 accumulate. Products of fp16 values are exact in
// fp32 either way, so both paths are numerically identical.
#if defined(__has_builtin) && __has_builtin(__builtin_amdgcn_fdot2)
__device__ inline float dot2f(uint32_t w, uint32_t z, float acc) {
    return __builtin_amdgcn_fdot2(u2h(w), u2h(z), acc, false);
}
#else
__device__ inline float dot2f(uint32_t w, uint32_t z, float acc) {
    half2_t hw = u2h(w), hz = u2h(z);
    acc = fmaf((float)hw.x, (float)hz.x, acc);
    return fmaf((float)hw.y, (float)hz.y, acc);
}
#endif

struct Params { const void* in[29]; };

// Software pipeline: tick s computes L0:h0, L1:h1 (1 behind), L2:h2 (2
// behind) concurrently; z (fp16) double-buffered; ONE barrier per tick.
__global__ __launch_bounds__(256)
__attribute__((amdgpu_waves_per_eu(1)))
void liquid_cfc_kernel(Params p, void* __restrict__ outp) {
    const int tid = threadIdx.x;   // == unit, state order [L0|L1|L2]
    const int b   = blockIdx.x;

    int lay, u, k;
    if (tid < H0_)       { lay = 0; u = tid;        k = K0_; }
    else if (tid < 128)  { lay = 1; u = tid - H0_;  k = K1_; }
    else                 { lay = 2; u = tid - 128;  k = K2_; }
    const int smin = lay, smax = lay + T_ - 1;

    const void* xp  = p.in[0];
    const void* h0p = p.in[1];
    // dict order per layer: m, W1, W2, Wa, Wb, b1, b2, ba, bb
    const void* Mp  = p.in[2 + 9 * lay + 0];
    const void* W1p = p.in[2 + 9 * lay + 1];
    const void* W2p = p.in[2 + 9 * lay + 2];
    const void* Wap = p.in[2 + 9 * lay + 3];
    const void* Wbp = p.in[2 + 9 * lay + 4];
    const void* B1p = p.in[2 + 9 * lay + 5];
    const void* B2p = p.in[2 + 9 * lay + 6];
    const void* Bap = p.in[2 + 9 * lay + 7];
    const void* Bbp = p.in[2 + 9 * lay + 8];

    // dtype probe on mask m_0 (values exactly 0.0/1.0)
    int dt;
    {
        const unsigned short* q = (const unsigned short*)p.in[2];
        bool anyf16 = false, lowNZ = false;
        for (int i = 0; i < 64; ++i) {
            unsigned short v = q[i];
            if (v == 0x3C00) anyf16 = true;
            if ((i & 1) == 0 && v != 0) lowNZ = true;
        }
        dt = anyf16 ? 2 : (lowNZ ? 1 : 0);
    }

    __shared__ alignas(16) unsigned short zh[2 * ZBUFV];  // fp16 z, dbuf
    __shared__ float4 wpcl[NG * 256];                     // folded Wa+Wb

    // zero z buffers (pad slots must stay finite-zero forever)
    {
        uint32_t* z32 = (uint32_t*)zh;
        for (int i = tid; i < ZBUFV; i += 256) z32[i] = 0;
    }

    // one-time: load + mask + fold. This lane holds its unit's ENTIRE row,
    // zero-padded to 92 pairs. wp1/wp2 -> 184 VGPRs; wpc -> LDS index-major.
    const int rowoff = u * k;
    uint32_t wp1[NW], wp2[NW];
#pragma unroll
    for (int i4 = 0; i4 < NG; ++i4) {
        uint32_t cw[4];
#pragma unroll
        for (int r = 0; r < 4; ++r) {
            const int j = 4 * i4 + r;
            const int c0 = 2 * j, c1 = c0 + 1;
            const bool v0 = (c0 < k);
            const bool v1 = (c1 < k);
            float m0 = 0.f, m1 = 0.f, v1a = 0.f, v1b = 0.f, v2a = 0.f,
                  v2b = 0.f, vca = 0.f, vcb = 0.f;
            if (v0) {
                m0  = ldany(Mp,  rowoff + c0, dt);
                v1a = ldany(W1p, rowoff + c0, dt);
                v2a = ldany(W2p, rowoff + c0, dt);
                vca = ldany(Wap, rowoff + c0, dt) + ldany(Wbp, rowoff + c0, dt);
            }
            if (v1) {
                m1  = ldany(Mp,  rowoff + c1, dt);
                v1b = ldany(W1p, rowoff + c1, dt);
                v2b = ldany(W2p, rowoff + c1, dt);
                vcb = ldany(Wap, rowoff + c1, dt) + ldany(Wbp, rowoff + c1, dt);
            }
            wp1[j] = packh2(v1a * m0, v1b * m1);
            wp2[j] = packh2(v2a * m0, v2b * m1);
            cw[r]  = packh2(vca * m0, vcb * m1);
        }
        float4 cv;
        cv.x = __builtin_bit_cast(float, cw[0]);
        cv.y = __builtin_bit_cast(float, cw[1]);
        cv.z = __builtin_bit_cast(float, cw[2]);
        cv.w = __builtin_bit_cast(float, cw[3]);
        wpcl[i4 * 256 + tid] = cv;   // lane-consecutive 16B, conflict-free
    }

    const float bias1 = ldany(B1p, u, dt);
    const float bias2 = ldany(B2p, u, dt);
    const float biasc = ldany(Bap, u, dt) + ldany(Bbp, u, dt);
    float hcur = ldany(h0p, (size_t)b * 256 + tid, dt);

    // write slots (fp16-value index within a z buffer):
    // z0=[x(64)|h0(77)] z1=[h0'(77)|h1(51)] z2=[h1'(51)|h2(128)]
    int ws0, ws1;
    if (lay == 0)      { ws0 = 64 + u;              ws1 = ZROWV + u; }
    else if (lay == 1) { ws0 = ZROWV + 77 + u;      ws1 = 2 * ZROWV + u; }
    else               { ws0 = 2 * ZROWV + 51 + u;  ws1 = 2 * ZROWV + 51 + u; }

    __syncthreads();   // zeroing + wpcl visible

    {   // h_init into both buffers (own slot each -> no race)
        unsigned short hh = __builtin_bit_cast(unsigned short, (_Float16)hcur);
        zh[ws0] = hh; zh[ZBUFV + ws0] = hh;
    }

    // x staging duty: 32 L1 lanes (tid 96..127), 2 values each -> z0.x[0..64)
    // as one u32 fp16-pair write. buf0.x = x(0); regs carry x(1).
    const bool isx = (tid >= 96) && (tid < 128);
    const int  xj  = tid - 96;
    const size_t xbase = (size_t)b * T_ * F_;
    const size_t obase = (size_t)b * T_ * H2_;
    float xf0 = 0.f, xf1 = 0.f;
    if (isx) {
        *(uint32_t*)&zh[2 * xj] =
            packh2(ldany(xp, xbase + 2 * xj, dt), ldany(xp, xbase + 2 * xj + 1, dt));
        xf0 = ldany(xp, xbase + F_ + 2 * xj, dt);
        xf1 = ldany(xp, xbase + F_ + 2 * xj + 1, dt);
    }
    __syncthreads();

    for (int s = 0; s < T_ + 2; ++s) {
        const int pr = s & 1;
        const unsigned short* rz = &zh[pr * ZBUFV + lay * ZROWV];
        unsigned short* wz = &zh[(pr ^ 1) * ZBUFV];

        // x pipeline at tick top: commit x(s+1) (in regs) into the write
        // buffer, then issue the x(s+2) load so it drains under the dot.
        if (isx) {
            if (s + 1 < T_) *(uint32_t*)&wz[2 * xj] = packh2(xf0, xf1);
            if (s + 2 < T_) {
                size_t xi = xbase + (size_t)(s + 2) * F_ + 2 * xj;
                xf0 = ldany(xp, xi, dt);
                xf1 = ldany(xp, xi + 1, dt);
            }
        }

        // full-row dot: 23 uniform groups (zero-padded weights x zero pads).
        // z reads are wave-uniform -> LDS broadcast; wpc reads lane-spread.
        float a1 = 0.f, a2 = 0.f, ac = 0.f;
        const float4* zv = (const float4*)rz;
#pragma unroll
        for (int g = 0; g < NG; ++g) {
            float4 q  = zv[g];
            float4 cv = wpcl[g * 256 + tid];
            uint32_t z0 = __builtin_bit_cast(uint32_t, q.x);
            uint32_t z1 = __builtin_bit_cast(uint32_t, q.y);
            uint32_t z2 = __builtin_bit_cast(uint32_t, q.z);
            uint32_t z3 = __builtin_bit_cast(uint32_t, q.w);
            uint32_t c0 = __builtin_bit_cast(uint32_t, cv.x);
            uint32_t c1 = __builtin_bit_cast(uint32_t, cv.y);
            uint32_t c2 = __builtin_bit_cast(uint32_t, cv.z);
            uint32_t c3 = __builtin_bit_cast(uint32_t, cv.w);
            a1 = dot2f(wp1[4 * g + 0], z0, a1);
            a1 = dot2f(wp1[4 * g + 1], z1, a1);
            a1 = dot2f(wp1[4 * g + 2], z2, a1);
            a1 = dot2f(wp1[4 * g + 3], z3, a1);
            a2 = dot2f(wp2[4 * g + 0], z0, a2);
            a2 = dot2f(wp2[4 * g + 1], z1, a2);
            a2 = dot2f(wp2[4 * g + 2], z2, a2);
            a2 = dot2f(wp2[4 * g + 3], z3, a2);
            ac = dot2f(c0, z0, ac);
            ac = dot2f(c1, z1, ac);
            ac = dot2f(c2, z2, ac);
            ac = dot2f(c3, z3, ac);
        }

        if (s >= smin && s <= smax) {
            float ff1 = tanh_f(bias1 + a1), ff2 = tanh_f(bias2 + a2),
                  ti = sigm_f(biasc + ac);
            float hn = ff1 + ti * (ff2 - ff1);
            unsigned short hh = __builtin_bit_cast(unsigned short, (_Float16)hn);
            wz[ws0] = hh; wz[ws1] = hh;
            hcur = hn;
            if (lay == 2) stout(outp, obase + (size_t)(s - 2) * H2_ + u, hn, dt);
        }
        __syncthreads();
    }

    // final hidden state hx = [L0 | L1 | L2] == lane order
    stout(outp, (size_t)B_ * T_ * H2_ + (size_t)b * 256 + tid, hcur, dt);
}

extern "C" void kernel_launch(void* const* d_in, const int* in_sizes, int n_in,
                              void* d_out, int out_size, void* d_ws, size_t ws_size,
                              hipStream_t stream) {
    (void)in_sizes; (void)out_size; (void)d_ws; (void)ws_size;
    Params p;
    const int m = (n_in < 29) ? n_in : 29;
    for (int i = 0; i < m; ++i) p.in[i] = d_in[i];
    liquid_cfc_kernel<<<dim3(B_), dim3(256), 0, stream>>>(p, d_out);
}